// Round 7
// baseline (370.730 us; speedup 1.0000x reference)
//
#include <hip/hip_runtime.h>
#include <cstdint>
#include <cstddef>

#define S_LEN 2048
#define DM    4096
#define NH    32
#define NKV   8
#define HDIM  128
#define EQ    4096   // NH*HDIM
#define EKV   1024   // NKV*HDIM
#define SC_LOG2E 0.1275325477889277f   // (1/sqrt(128)) * log2(e)

typedef unsigned short u16;
typedef short bf16x8 __attribute__((ext_vector_type(8)));
typedef float f32x4  __attribute__((ext_vector_type(4)));

__device__ __forceinline__ u16 f2bf(float f) {
  union { float f; unsigned u; } v; v.f = f;
  unsigned r = v.u + 0x7FFFu + ((v.u >> 16) & 1u);
  return (u16)(r >> 16);
}
__device__ __forceinline__ float bf2f(u16 b) {
  union { unsigned u; float f; } v; v.u = ((unsigned)b) << 16;
  return v.f;
}
__device__ __forceinline__ void glds16(const void* g, void* l) {
  __builtin_amdgcn_global_load_lds((const __attribute__((address_space(1))) void*)g,
                                   (__attribute__((address_space(3))) void*)l, 16, 0, 0);
}

// ---------------------------------------------------------------- cast fp32->bf16
__global__ void cast_all(const float* __restrict__ x, const float* __restrict__ wq,
                         const float* __restrict__ wk, const float* __restrict__ wv,
                         const float* __restrict__ wo,
                         u16* __restrict__ xb, u16* __restrict__ wqb,
                         u16* __restrict__ wkb, u16* __restrict__ wvb,
                         u16* __restrict__ wob) {
  const size_t stride = (size_t)gridDim.x * blockDim.x;
  for (size_t u = (size_t)blockIdx.x * blockDim.x + threadIdx.x; u < 12582912u; u += stride) {
    const float* in; u16* outp; size_t i;
    if (u < 2097152u)      { in = x;  outp = xb;  i = u; }
    else if (u < 6291456u) { in = wq; outp = wqb; i = u - 2097152u; }
    else if (u < 7340032u) { in = wk; outp = wkb; i = u - 6291456u; }
    else if (u < 8388608u) { in = wv; outp = wvb; i = u - 7340032u; }
    else                   { in = wo; outp = wob; i = u - 8388608u; }
    float4 f = ((const float4*)in)[i];
    ushort4 b;
    b.x = f2bf(f.x); b.y = f2bf(f.y); b.z = f2bf(f.z); b.w = f2bf(f.w);
    ((ushort4*)outp)[i] = b;
  }
}

// ---------------------------------------------------------------- 2-wave wide-tile GEMM
// C = A * B^T, bf16 row-major. Block = 128 threads = 2 waves side by side.
// Wave tile 128 x (16*FN): FN=6 (QKV, 54.9 FLOP/LDS-byte) or FN=4 (O, 42.7).
// LDS-read demand now BELOW MFMA demand (old 64x96 waves were LDS-saturated
// at 38 FLOP/B -> T_ktile ~= pure LDS issue time; R6 counters). BK=64,
// double-buffered: QKV 80 KB, O 64 KB -> 2 blocks/CU; 4 waves/CU = 1/SIMD,
// so __launch_bounds__(128,1) permits the 192-reg accumulator without spill.
// Loop: stage(next tile, buf^1) -> ds_read+MFMA(cur) -> __syncthreads -> flip.
// 16B-unit XOR swizzle u^=(row&7) on pre-swizzled global source (linear glds
// dest) + swizzled ds_read address: measured 0 bank conflicts (R5/R6).
template<int UN>
__device__ __forceinline__ void stage128(const u16* __restrict__ g, int ldg, int k0,
                                         u16* ldsp, int t) {
  const int wb = t & ~63;
#pragma unroll
  for (int j = 0; j < UN / 128; ++j) {
    const int U = j * 128 + t;
    const int row = U >> 3, u = U & 7;
    const int uu = u ^ (row & 7);
    glds16(g + (size_t)row * ldg + k0 + uu * 8, ldsp + (size_t)(j * 128 + wb) * 8);
  }
}

template<int FN, bool QKV3>
__global__ __launch_bounds__(128, 1)
void gemm2w(const u16* __restrict__ A, const u16* __restrict__ B,
            void* __restrict__ Cq, u16* __restrict__ Ck, u16* __restrict__ Cv,
            int K) {
  constexpr int BN = 32 * FN;          // block N (2 waves x 16*FN)
  constexpr int AT = 128 * 64;         // u16 per A tile (16 KB)
  constexpr int BT = BN * 64;          // u16 per B tile
  __shared__ u16 lds[2 * (AT + BT)];   // A0@0, A1@AT, B0@2AT, B1@2AT+BT
  const int t = threadIdx.x;
  const int l = t & 63, lr = l & 15, lg = l >> 4;
  const int wn = t >> 6;
  const int m0 = blockIdx.y * 128, n0 = blockIdx.x * BN;
  const int KT = K >> 6;

  const u16* Ab = A + (size_t)m0 * K;
  const u16* Bb = B + (size_t)n0 * K;

  f32x4 acc[8][FN] = {};

  stage128<1024>(Ab, K, 0, &lds[0], t);
  stage128<BT / 8>(Bb, K, 0, &lds[2 * AT], t);
  __syncthreads();

  int cur = 0;
#pragma unroll 1
  for (int tau = 0; tau < KT; ++tau) {
    const int kn = (tau + 1 < KT ? tau + 1 : KT - 1) * 64;
    stage128<1024>(Ab, K, kn, &lds[(cur ^ 1) * AT], t);
    stage128<BT / 8>(Bb, K, kn, &lds[2 * AT + (cur ^ 1) * BT], t);

    const int aB = cur * AT;
    const int bB = 2 * AT + cur * BT;

#pragma unroll
    for (int kk = 0; kk < 2; ++kk) {
      bf16x8 af[8], bf[FN];
#pragma unroll
      for (int mf = 0; mf < 8; ++mf) {
        const int row = mf * 16 + lr;
        const int us = ((kk * 4 + lg) ^ (row & 7)) * 8;
        af[mf] = *(const bf16x8*)&lds[aB + row * 64 + us];
      }
#pragma unroll
      for (int nf = 0; nf < FN; ++nf) {
        const int row = wn * (16 * FN) + nf * 16 + lr;
        const int us = ((kk * 4 + lg) ^ (row & 7)) * 8;
        bf[nf] = *(const bf16x8*)&lds[bB + row * 64 + us];
      }
#pragma unroll
      for (int mf = 0; mf < 8; ++mf)
#pragma unroll
        for (int nf = 0; nf < FN; ++nf)
          acc[mf][nf] = __builtin_amdgcn_mfma_f32_16x16x32_bf16(af[mf], bf[nf], acc[mf][nf], 0, 0, 0);
    }
    __syncthreads();
    cur ^= 1;
  }

  // epilogue; fragment cols are 16-aligned so QKV routing is per-fragment
#pragma unroll
  for (int mf = 0; mf < 8; ++mf) {
    const int row = m0 + mf * 16 + lg * 4;
#pragma unroll
    for (int nf = 0; nf < FN; ++nf) {
      const int gc = n0 + wn * (16 * FN) + nf * 16 + lr;
#pragma unroll
      for (int r = 0; r < 4; ++r) {
        if constexpr (QKV3) {
          if (gc < 4096)
            ((u16*)Cq)[(size_t)(row + r) * 4096 + gc] = f2bf(acc[mf][nf][r]);
          else if (gc < 5120)
            Ck[(size_t)(row + r) * 1024 + (gc - 4096)] = f2bf(acc[mf][nf][r]);
          else
            Cv[(size_t)(row + r) * 1024 + (gc - 5120)] = f2bf(acc[mf][nf][r]);
        } else {
          ((float*)Cq)[(size_t)(row + r) * 4096 + gc] = acc[mf][nf][r];
        }
      }
    }
  }
}

// ---------------------------------------------------------------- RoPE (q then k)
__global__ void rope_all(u16* __restrict__ qd, u16* __restrict__ kd,
                         const float* __restrict__ cosb, const float* __restrict__ sinb,
                         const int* __restrict__ sidx) {
  const int u = blockIdx.x * blockDim.x + threadIdx.x;
  u16* base; int s, b;
  if (u < 1048576) {
    base = qd + (size_t)u * 8;
    s = u >> 9;
    b = u & 15;
  } else if (u < 1310720) {
    const int u2 = u - 1048576;
    base = kd + (size_t)u2 * 8;
    s = u2 >> 7;
    b = u2 & 15;
  } else return;
  const int pos = sidx[s];
  const float4 c  = *(const float4*)&cosb[pos * 64 + b * 4];
  const float4 sn = *(const float4*)&sinb[pos * 64 + b * 4];
  uint4 raw = *(uint4*)base;
  u16* pe = (u16*)&raw;
  const float cc[4] = {c.x, c.y, c.z, c.w};
  const float ss[4] = {sn.x, sn.y, sn.z, sn.w};
#pragma unroll
  for (int j = 0; j < 4; ++j) {
    const float xr = bf2f(pe[2 * j]), xi = bf2f(pe[2 * j + 1]);
    pe[2 * j]     = f2bf(xr * cc[j] - xi * ss[j]);
    pe[2 * j + 1] = f2bf(xr * ss[j] + xi * cc[j]);
  }
  *(uint4*)base = raw;
}

// ---------------------------------------------------------------- V transpose
__global__ void transpose_v(const u16* __restrict__ v, u16* __restrict__ vt) {
  __shared__ u16 tile[32][33];
  const int tx = threadIdx.x, ty = threadIdx.y;
  const int c0 = blockIdx.x * 32, s0 = blockIdx.y * 32;
#pragma unroll
  for (int j = 0; j < 32; j += 8)
    tile[ty + j][tx] = v[(size_t)(s0 + ty + j) * EKV + c0 + tx];
  __syncthreads();
#pragma unroll
  for (int j = 0; j < 32; j += 8)
    vt[(size_t)(c0 + ty + j) * S_LEN + s0 + tx] = tile[tx][ty + j];
}

// ---------------------------------------------------------------- flash attention
// Causal-paired blocks (p, 31-p): 33 KV-tiles per block, perfectly balanced.
// K/V double-buffered: stage(tk+1 -> buf^1) issued BEFORE computing tile tk,
// ONE __syncthreads per tile (drains the prefetch + fences the flip). 74.7 KB
// LDS -> 2 blocks/CU.
#define ATTN_STAGE(TK, BUF) { \
  const int kv0s = (TK) * 64; \
  _Pragma("unroll") \
  for (int hh = 0; hh < 4; ++hh) { \
    const int f = hh * 256 + t; \
    { const int row = f >> 4, uu = f & 15, us = uu ^ (row & 7); \
      glds16(&k[(size_t)(kv0s + row) * EKV + kvh * HDIM + us * 8], &lK[BUF][(hh * 256 + wb) * 8]); } \
    { const int row = f >> 3, uu = f & 7, us = uu ^ (row & 7); \
      glds16(&vt[(size_t)(kvh * HDIM + row) * S_LEN + kv0s + us * 8], &lV[BUF][(hh * 256 + wb) * 8]); } \
  } }

__global__ __launch_bounds__(256, 2)
void attn_fwd(const u16* __restrict__ q, const u16* __restrict__ k,
              const u16* __restrict__ vt, u16* __restrict__ ao) {
  __shared__ u16 lK[2][64 * 128];
  __shared__ u16 lV[2][128 * 64];
  __shared__ u16 lP[4 * 16 * 72];
  const int t = threadIdx.x, w = t >> 6, l = t & 63;
  const int lr = l & 15, lg = l >> 4;
  const int wb = t & ~63;
  const int p = blockIdx.x, h = blockIdx.y;
  const int kvh = h >> 2;
  u16* lPw = &lP[w * (16 * 72)];

#pragma unroll 1
  for (int ph = 0; ph < 2; ++ph) {
    const int qt = ph ? (31 - p) : p;
    const int q0 = qt * 64 + w * 16;
    const int nt = qt + 1;

    bf16x8 qa[4];
#pragma unroll
    for (int kc = 0; kc < 4; ++kc)
      qa[kc] = *(const bf16x8*)&q[(size_t)(q0 + lr) * EQ + h * HDIM + kc * 32 + lg * 8];

    f32x4 o[8] = {};
    float mrun[4], lrun[4];
#pragma unroll
    for (int r = 0; r < 4; ++r) { mrun[r] = -1e30f; lrun[r] = 0.f; }

    int cur = 0;
    ATTN_STAGE(0, 0);
    __syncthreads();

#pragma unroll 1
    for (int tk = 0; tk < nt; ++tk) {
      const int kv0 = tk * 64;
      if (tk + 1 < nt) ATTN_STAGE(tk + 1, cur ^ 1);
      const u16* lKc = lK[cur];
      const u16* lVc = lV[cur];

      f32x4 sc[4] = {};
#pragma unroll
      for (int n = 0; n < 4; ++n) {
#pragma unroll
        for (int kc = 0; kc < 4; ++kc) {
          const int row = n * 16 + lr;
          const int us = (kc * 4 + lg) ^ (row & 7);
          bf16x8 bk = *(const bf16x8*)&lKc[row * 128 + us * 8];
          sc[n] = __builtin_amdgcn_mfma_f32_16x16x32_bf16(qa[kc], bk, sc[n], 0, 0, 0);
        }
      }

#pragma unroll
      for (int n = 0; n < 4; ++n) {
        const int kvc = kv0 + n * 16 + lr;
#pragma unroll
        for (int r = 0; r < 4; ++r) {
          const int qr = q0 + lg * 4 + r;
          const float v = sc[n][r] * SC_LOG2E;
          sc[n][r] = (kvc > qr) ? -1e30f : v;
        }
      }
#pragma unroll
      for (int r = 0; r < 4; ++r) {
        float v = fmaxf(fmaxf(sc[0][r], sc[1][r]), fmaxf(sc[2][r], sc[3][r]));
        v = fmaxf(v, __shfl_xor(v, 1));
        v = fmaxf(v, __shfl_xor(v, 2));
        v = fmaxf(v, __shfl_xor(v, 4));
        v = fmaxf(v, __shfl_xor(v, 8));
        const float mn = fmaxf(mrun[r], v);
        const float sf = __builtin_amdgcn_exp2f(mrun[r] - mn);
        mrun[r] = mn;
        float rs = 0.f;
#pragma unroll
        for (int n = 0; n < 4; ++n) {
          const float pv = __builtin_amdgcn_exp2f(sc[n][r] - mn);
          sc[n][r] = pv;
          rs += pv;
        }
        rs += __shfl_xor(rs, 1);
        rs += __shfl_xor(rs, 2);
        rs += __shfl_xor(rs, 4);
        rs += __shfl_xor(rs, 8);
        lrun[r] = lrun[r] * sf + rs;
#pragma unroll
        for (int nh = 0; nh < 8; ++nh) o[nh][r] *= sf;
      }
#pragma unroll
      for (int n = 0; n < 4; ++n)
#pragma unroll
        for (int r = 0; r < 4; ++r)
          lPw[(lg * 4 + r) * 72 + n * 16 + lr] = f2bf(sc[n][r]);

#pragma unroll
      for (int kc2 = 0; kc2 < 2; ++kc2) {
        bf16x8 pa = *(const bf16x8*)&lPw[lr * 72 + kc2 * 32 + lg * 8];
#pragma unroll
        for (int nh = 0; nh < 8; ++nh) {
          const int row = nh * 16 + lr;
          const int us = (kc2 * 4 + lg) ^ (row & 7);
          bf16x8 bv = *(const bf16x8*)&lVc[row * 64 + us * 8];
          o[nh] = __builtin_amdgcn_mfma_f32_16x16x32_bf16(pa, bv, o[nh], 0, 0, 0);
        }
      }
      __syncthreads();
      cur ^= 1;
    }

#pragma unroll
    for (int nh = 0; nh < 8; ++nh)
#pragma unroll
      for (int r = 0; r < 4; ++r) {
        const float val = o[nh][r] / lrun[r];
        ao[(size_t)(q0 + lg * 4 + r) * EQ + h * HDIM + nh * 16 + lr] = f2bf(val);
      }
  }
}

// ---------------------------------------------------------------- launch
extern "C" void kernel_launch(void* const* d_in, const int* in_sizes, int n_in,
                              void* d_out, int out_size, void* d_ws, size_t ws_size,
                              hipStream_t stream) {
  (void)in_sizes; (void)n_in; (void)out_size; (void)ws_size;
  const float* x    = (const float*)d_in[0];
  const float* wq   = (const float*)d_in[1];
  const float* wk   = (const float*)d_in[2];
  const float* wv   = (const float*)d_in[3];
  const float* wo   = (const float*)d_in[4];
  const float* cosb = (const float*)d_in[7];
  const float* sinb = (const float*)d_in[8];
  const int*   sidx = (const int*)d_in[10];
  float* out = (float*)d_out;

  // workspace layout; wqb/wkb/wvb are contiguous so B_qkv = [wq;wk;wv]
  u16* ws  = (u16*)d_ws;
  u16* xb  = ws;                                  // 2048*4096
  u16* wqb = xb  + (size_t)S_LEN * DM;            // 4096*4096
  u16* wkb = wqb + (size_t)EQ * DM;               // 1024*4096
  u16* wvb = wkb + (size_t)EKV * DM;              // 1024*4096
  u16* wob = wvb + (size_t)EKV * DM;              // 4096*4096
  u16* qb  = wob + (size_t)DM * EQ;               // 2048*4096
  u16* kb  = qb  + (size_t)S_LEN * EQ;            // 2048*1024
  u16* vb  = kb  + (size_t)S_LEN * EKV;           // 2048*1024
  u16* vtb = vb  + (size_t)S_LEN * EKV;           // 1024*2048
  u16* aob = vtb + (size_t)S_LEN * EKV;           // 2048*4096

  cast_all<<<2048, 256, 0, stream>>>(x, wq, wk, wv, wo, xb, wqb, wkb, wvb, wob);
  // fused QKV projection: B = [wq;wk;wv] (6144 x 4096), BN=192 -> 32x16 = 512 blocks (2/CU)
  gemm2w<6, true><<<dim3(32, 16), 128, 0, stream>>>(xb, wqb, qb, kb, vb, DM);
  rope_all<<<5120, 256, 0, stream>>>(qb, kb, cosb, sinb, sidx);
  transpose_v<<<dim3(EKV / 32, S_LEN / 32), dim3(32, 8), 0, stream>>>(vb, vtb);
  attn_fwd<<<dim3(16, NH), 256, 0, stream>>>(qb, kb, vtb, aob);
  // O projection: BN=128 -> 32x16 = 512 blocks (2/CU)
  gemm2w<4, false><<<dim3(32, 16), 128, 0, stream>>>(aob, wob, out, nullptr, nullptr, EQ);
}

// Round 8
// 320.732 us; speedup vs baseline: 1.1559x; 1.1559x over previous
//
#include <hip/hip_runtime.h>
#include <cstdint>
#include <cstddef>

#define S_LEN 2048
#define DM    4096
#define NH    32
#define NKV   8
#define HDIM  128
#define EQ    4096   // NH*HDIM
#define EKV   1024   // NKV*HDIM
#define SC_LOG2E 0.1275325477889277f   // (1/sqrt(128)) * log2(e)

typedef unsigned short u16;
typedef short bf16x8 __attribute__((ext_vector_type(8)));
typedef float f32x4  __attribute__((ext_vector_type(4)));

__device__ __forceinline__ u16 f2bf(float f) {
  union { float f; unsigned u; } v; v.f = f;
  unsigned r = v.u + 0x7FFFu + ((v.u >> 16) & 1u);
  return (u16)(r >> 16);
}
__device__ __forceinline__ float bf2f(u16 b) {
  union { unsigned u; float f; } v; v.u = ((unsigned)b) << 16;
  return v.f;
}
__device__ __forceinline__ void glds16(const void* g, void* l) {
  __builtin_amdgcn_global_load_lds((const __attribute__((address_space(1))) void*)g,
                                   (__attribute__((address_space(3))) void*)l, 16, 0, 0);
}

// ---------------------------------------------------------------- cast fp32->bf16
__global__ void cast_all(const float* __restrict__ x, const float* __restrict__ wq,
                         const float* __restrict__ wk, const float* __restrict__ wv,
                         const float* __restrict__ wo,
                         u16* __restrict__ xb, u16* __restrict__ wqb,
                         u16* __restrict__ wkb, u16* __restrict__ wvb,
                         u16* __restrict__ wob) {
  const size_t stride = (size_t)gridDim.x * blockDim.x;
  for (size_t u = (size_t)blockIdx.x * blockDim.x + threadIdx.x; u < 12582912u; u += stride) {
    const float* in; u16* outp; size_t i;
    if (u < 2097152u)      { in = x;  outp = xb;  i = u; }
    else if (u < 6291456u) { in = wq; outp = wqb; i = u - 2097152u; }
    else if (u < 7340032u) { in = wk; outp = wkb; i = u - 6291456u; }
    else if (u < 8388608u) { in = wv; outp = wvb; i = u - 7340032u; }
    else                   { in = wo; outp = wob; i = u - 8388608u; }
    float4 f = ((const float4*)in)[i];
    ushort4 b;
    b.x = f2bf(f.x); b.y = f2bf(f.y); b.z = f2bf(f.z); b.w = f2bf(f.w);
    ((ushort4*)outp)[i] = b;
  }
}

// ---------------------------------------------------------------- 2-phase GEMM, BM=128, BN=64*NF
// (R6 structure, verbatim semantics — proven 104/70 us, MfmaUtil 44%, 0 conflicts.)
// 4 waves (2x2), wave-tile 64 x 32*NF. BK=64, double-buffered LDS: 80 KB (NF=3)
// or 64 KB (NF=2) -> 2 blocks/CU, 2 waves/SIMD (>=2/SIMD is a hard floor: R7's
// 1/SIMD variant starved at MfmaUtil 30%). Loop: stage(next,buf^1) ->
// ds_read+MFMA(cur) -> __syncthreads -> flip. 16B-unit XOR swizzle u^=(row&7)
// on pre-swizzled global source (linear glds dest) + swizzled ds_read address.
template<int UN>
__device__ __forceinline__ void stage_t(const u16* __restrict__ g, int ldg, int k0,
                                        u16* ldsp, int t) {
  const int wb = t & ~63;
#pragma unroll
  for (int j = 0; j < UN / 256; ++j) {
    const int U = j * 256 + t;
    const int row = U >> 3, u = U & 7;
    const int uu = u ^ (row & 7);
    glds16(g + (size_t)row * ldg + k0 + uu * 8, ldsp + (size_t)(j * 256 + wb) * 8);
  }
}

template<int NF, bool QKV3>
__global__ __launch_bounds__(256, 2)
void gemm2p(const u16* __restrict__ A, const u16* __restrict__ B,
            void* __restrict__ Cq, u16* __restrict__ Ck, u16* __restrict__ Cv,
            int K) {
  constexpr int BN = 64 * NF;
  constexpr int AT = 128 * 64;        // u16 per A tile (8192)
  constexpr int BT = BN * 64;         // u16 per B tile
  __shared__ u16 lds[2 * (AT + BT)];  // A0 @0, A1 @AT, B0 @2*AT, B1 @2*AT+BT
  const int t = threadIdx.x;
  const int l = t & 63, lr = l & 15, lg = l >> 4;
  const int wid = t >> 6, wm = wid >> 1, wn = wid & 1;
  const int m0 = blockIdx.y * 128, n0 = blockIdx.x * BN;
  const int KT = K >> 6;

  const u16* Ab = A + (size_t)m0 * K;
  const u16* Bb = B + (size_t)n0 * K;

  f32x4 acc[4][2 * NF] = {};

  stage_t<1024>(Ab, K, 0, &lds[0], t);
  stage_t<BT / 8>(Bb, K, 0, &lds[2 * AT], t);
  __syncthreads();

  int cur = 0;
#pragma unroll 1
  for (int tau = 0; tau < KT; ++tau) {
    const int kn = (tau + 1 < KT ? tau + 1 : KT - 1) * 64;
    stage_t<1024>(Ab, K, kn, &lds[(cur ^ 1) * AT], t);
    stage_t<BT / 8>(Bb, K, kn, &lds[2 * AT + (cur ^ 1) * BT], t);

    const int aBase = cur * AT;
    const int bBase = 2 * AT + cur * BT;

    bf16x8 af[4][2];
#pragma unroll
    for (int mf = 0; mf < 4; ++mf)
#pragma unroll
      for (int kk = 0; kk < 2; ++kk) {
        const int row = wm * 64 + mf * 16 + lr;
        const int uu = ((kk * 4 + lg) ^ (row & 7)) * 8;
        af[mf][kk] = *(const bf16x8*)&lds[aBase + row * 64 + uu];
      }

#pragma unroll
    for (int n = 0; n < 2 * NF; ++n) {
      const int brow = wn * (32 * NF) + n * 16 + lr;
      const int u0 = ((0 * 4 + lg) ^ (brow & 7)) * 8;
      const int u1 = ((1 * 4 + lg) ^ (brow & 7)) * 8;
      bf16x8 b0 = *(const bf16x8*)&lds[bBase + brow * 64 + u0];
      bf16x8 b1 = *(const bf16x8*)&lds[bBase + brow * 64 + u1];
#pragma unroll
      for (int mf = 0; mf < 4; ++mf) {
        acc[mf][n] = __builtin_amdgcn_mfma_f32_16x16x32_bf16(af[mf][0], b0, acc[mf][n], 0, 0, 0);
        acc[mf][n] = __builtin_amdgcn_mfma_f32_16x16x32_bf16(af[mf][1], b1, acc[mf][n], 0, 0, 0);
      }
    }
    __syncthreads();
    cur ^= 1;
  }

  // epilogue; fragment cols are 16-aligned so QKV routing is per-fragment
#pragma unroll
  for (int mf = 0; mf < 4; ++mf) {
    const int row = m0 + wm * 64 + mf * 16 + lg * 4;
#pragma unroll
    for (int n = 0; n < 2 * NF; ++n) {
      const int gc = n0 + wn * (32 * NF) + n * 16 + lr;
#pragma unroll
      for (int r = 0; r < 4; ++r) {
        if constexpr (QKV3) {
          if (gc < 4096)
            ((u16*)Cq)[(size_t)(row + r) * 4096 + gc] = f2bf(acc[mf][n][r]);
          else if (gc < 5120)
            Ck[(size_t)(row + r) * 1024 + (gc - 4096)] = f2bf(acc[mf][n][r]);
          else
            Cv[(size_t)(row + r) * 1024 + (gc - 5120)] = f2bf(acc[mf][n][r]);
        } else {
          ((float*)Cq)[(size_t)(row + r) * 4096 + gc] = acc[mf][n][r];
        }
      }
    }
  }
}

// ---------------------------------------------------------------- RoPE (q then k)
__global__ void rope_all(u16* __restrict__ qd, u16* __restrict__ kd,
                         const float* __restrict__ cosb, const float* __restrict__ sinb,
                         const int* __restrict__ sidx) {
  const int u = blockIdx.x * blockDim.x + threadIdx.x;
  u16* base; int s, b;
  if (u < 1048576) {
    base = qd + (size_t)u * 8;
    s = u >> 9;
    b = u & 15;
  } else if (u < 1310720) {
    const int u2 = u - 1048576;
    base = kd + (size_t)u2 * 8;
    s = u2 >> 7;
    b = u2 & 15;
  } else return;
  const int pos = sidx[s];
  const float4 c  = *(const float4*)&cosb[pos * 64 + b * 4];
  const float4 sn = *(const float4*)&sinb[pos * 64 + b * 4];
  uint4 raw = *(uint4*)base;
  u16* pe = (u16*)&raw;
  const float cc[4] = {c.x, c.y, c.z, c.w};
  const float ss[4] = {sn.x, sn.y, sn.z, sn.w};
#pragma unroll
  for (int j = 0; j < 4; ++j) {
    const float xr = bf2f(pe[2 * j]), xi = bf2f(pe[2 * j + 1]);
    pe[2 * j]     = f2bf(xr * cc[j] - xi * ss[j]);
    pe[2 * j + 1] = f2bf(xr * ss[j] + xi * cc[j]);
  }
  *(uint4*)base = raw;
}

// ---------------------------------------------------------------- V transpose
__global__ void transpose_v(const u16* __restrict__ v, u16* __restrict__ vt) {
  __shared__ u16 tile[32][33];
  const int tx = threadIdx.x, ty = threadIdx.y;
  const int c0 = blockIdx.x * 32, s0 = blockIdx.y * 32;
#pragma unroll
  for (int j = 0; j < 32; j += 8)
    tile[ty + j][tx] = v[(size_t)(s0 + ty + j) * EKV + c0 + tx];
  __syncthreads();
#pragma unroll
  for (int j = 0; j < 32; j += 8)
    vt[(size_t)(c0 + ty + j) * S_LEN + s0 + tx] = tile[tx][ty + j];
}

// ---------------------------------------------------------------- flash attention
// MERGED causal pair: block (p,h) sweeps KV ONCE (nt = 32-p tiles of 64) and
// computes BOTH q-tiles against each staged tile: tile B (qt=31-p) always,
// tile A (qt=p) while tk<=p (wave-uniform guard). Stages+barriers: 33 ->
// 32-p (mean 24.5); compute total unchanged (p+1 + 32-p = 33 wave-steps).
// K/V double-buffered (stage tk+1 before computing tk, one barrier/tile);
// 73 KB LDS -> 2 blocks/CU = 2 waves/SIMD. P round-trips through per-wave
// padded LDS, reused A-then-B (in-order per-wave LDS ops + compiler lgkmcnt).
#define ATTN_STAGE(TK, BUF) { \
  const int kv0s = (TK) * 64; \
  _Pragma("unroll") \
  for (int hh = 0; hh < 4; ++hh) { \
    const int f = hh * 256 + t; \
    { const int row = f >> 4, uu = f & 15, us = uu ^ (row & 7); \
      glds16(&k[(size_t)(kv0s + row) * EKV + kvh * HDIM + us * 8], &lK[BUF][(hh * 256 + wb) * 8]); } \
    { const int row = f >> 3, uu = f & 7, us = uu ^ (row & 7); \
      glds16(&vt[(size_t)(kvh * HDIM + row) * S_LEN + kv0s + us * 8], &lV[BUF][(hh * 256 + wb) * 8]); } \
  } }

// one q-tile step against the staged KV tile (all names static-indexed)
#define TILE_STEP(QA, O, MR, LR, Q0) { \
  f32x4 sc[4] = {}; \
  _Pragma("unroll") \
  for (int n = 0; n < 4; ++n) { \
    _Pragma("unroll") \
    for (int kc = 0; kc < 4; ++kc) { \
      const int row = n * 16 + lr; \
      const int us = (kc * 4 + lg) ^ (row & 7); \
      bf16x8 bk = *(const bf16x8*)&lKc[row * 128 + us * 8]; \
      sc[n] = __builtin_amdgcn_mfma_f32_16x16x32_bf16(QA[kc], bk, sc[n], 0, 0, 0); \
    } \
  } \
  _Pragma("unroll") \
  for (int n = 0; n < 4; ++n) { \
    const int kvc = kv0 + n * 16 + lr; \
    _Pragma("unroll") \
    for (int r = 0; r < 4; ++r) { \
      const int qr = (Q0) + lg * 4 + r; \
      const float vv = sc[n][r] * SC_LOG2E; \
      sc[n][r] = (kvc > qr) ? -1e30f : vv; \
    } \
  } \
  _Pragma("unroll") \
  for (int r = 0; r < 4; ++r) { \
    float v = fmaxf(fmaxf(sc[0][r], sc[1][r]), fmaxf(sc[2][r], sc[3][r])); \
    v = fmaxf(v, __shfl_xor(v, 1)); \
    v = fmaxf(v, __shfl_xor(v, 2)); \
    v = fmaxf(v, __shfl_xor(v, 4)); \
    v = fmaxf(v, __shfl_xor(v, 8)); \
    const float mn = fmaxf(MR[r], v); \
    const float sf = __builtin_amdgcn_exp2f(MR[r] - mn); \
    MR[r] = mn; \
    float rs = 0.f; \
    _Pragma("unroll") \
    for (int n = 0; n < 4; ++n) { \
      const float pv = __builtin_amdgcn_exp2f(sc[n][r] - mn); \
      sc[n][r] = pv; \
      rs += pv; \
    } \
    rs += __shfl_xor(rs, 1); \
    rs += __shfl_xor(rs, 2); \
    rs += __shfl_xor(rs, 4); \
    rs += __shfl_xor(rs, 8); \
    LR[r] = LR[r] * sf + rs; \
    _Pragma("unroll") \
    for (int nh = 0; nh < 8; ++nh) O[nh][r] *= sf; \
  } \
  _Pragma("unroll") \
  for (int n = 0; n < 4; ++n) \
    _Pragma("unroll") \
    for (int r = 0; r < 4; ++r) \
      lPw[(lg * 4 + r) * 72 + n * 16 + lr] = f2bf(sc[n][r]); \
  _Pragma("unroll") \
  for (int kc2 = 0; kc2 < 2; ++kc2) { \
    bf16x8 pa = *(const bf16x8*)&lPw[lr * 72 + kc2 * 32 + lg * 8]; \
    _Pragma("unroll") \
    for (int nh = 0; nh < 8; ++nh) { \
      const int row = nh * 16 + lr; \
      const int us = (kc2 * 4 + lg) ^ (row & 7); \
      bf16x8 bv = *(const bf16x8*)&lVc[row * 64 + us * 8]; \
      O[nh] = __builtin_amdgcn_mfma_f32_16x16x32_bf16(pa, bv, O[nh], 0, 0, 0); \
    } \
  } }

__global__ __launch_bounds__(256, 2)
void attn_fwd(const u16* __restrict__ q, const u16* __restrict__ k,
              const u16* __restrict__ vt, u16* __restrict__ ao) {
  __shared__ u16 lK[2][64 * 128];
  __shared__ u16 lV[2][128 * 64];
  __shared__ u16 lP[4 * 16 * 72];
  const int t = threadIdx.x, w = t >> 6, l = t & 63;
  const int lr = l & 15, lg = l >> 4;
  const int wb = t & ~63;
  const int p = blockIdx.x, h = blockIdx.y;
  const int kvh = h >> 2;
  u16* lPw = &lP[w * (16 * 72)];

  const int q0A = p * 64 + w * 16;          // q-tile A = p (active while tk<=p)
  const int q0B = (31 - p) * 64 + w * 16;   // q-tile B = 31-p (always active)
  const int nt = 32 - p;                    // KV tiles for B (covers A too)

  bf16x8 qaA[4], qaB[4];
#pragma unroll
  for (int kc = 0; kc < 4; ++kc) {
    qaA[kc] = *(const bf16x8*)&q[(size_t)(q0A + lr) * EQ + h * HDIM + kc * 32 + lg * 8];
    qaB[kc] = *(const bf16x8*)&q[(size_t)(q0B + lr) * EQ + h * HDIM + kc * 32 + lg * 8];
  }

  f32x4 oA[8] = {}, oB[8] = {};
  float mA[4], lA[4], mB[4], lB[4];
#pragma unroll
  for (int r = 0; r < 4; ++r) { mA[r] = -1e30f; lA[r] = 0.f; mB[r] = -1e30f; lB[r] = 0.f; }

  int cur = 0;
  ATTN_STAGE(0, 0);
  __syncthreads();

#pragma unroll 1
  for (int tk = 0; tk < nt; ++tk) {
    const int kv0 = tk * 64;
    if (tk + 1 < nt) ATTN_STAGE(tk + 1, cur ^ 1);
    const u16* lKc = lK[cur];
    const u16* lVc = lV[cur];

    TILE_STEP(qaB, oB, mB, lB, q0B);
    if (tk <= p) {
      TILE_STEP(qaA, oA, mA, lA, q0A);
    }
    __syncthreads();
    cur ^= 1;
  }

#pragma unroll
  for (int nh = 0; nh < 8; ++nh)
#pragma unroll
    for (int r = 0; r < 4; ++r) {
      const int col = h * HDIM + nh * 16 + lr;
      ao[(size_t)(q0A + lg * 4 + r) * EQ + col] = f2bf(oA[nh][r] / lA[r]);
      ao[(size_t)(q0B + lg * 4 + r) * EQ + col] = f2bf(oB[nh][r] / lB[r]);
    }
}

// ---------------------------------------------------------------- launch
extern "C" void kernel_launch(void* const* d_in, const int* in_sizes, int n_in,
                              void* d_out, int out_size, void* d_ws, size_t ws_size,
                              hipStream_t stream) {
  (void)in_sizes; (void)n_in; (void)out_size; (void)ws_size;
  const float* x    = (const float*)d_in[0];
  const float* wq   = (const float*)d_in[1];
  const float* wk   = (const float*)d_in[2];
  const float* wv   = (const float*)d_in[3];
  const float* wo   = (const float*)d_in[4];
  const float* cosb = (const float*)d_in[7];
  const float* sinb = (const float*)d_in[8];
  const int*   sidx = (const int*)d_in[10];
  float* out = (float*)d_out;

  // workspace layout; wqb/wkb/wvb are contiguous so B_qkv = [wq;wk;wv]
  u16* ws  = (u16*)d_ws;
  u16* xb  = ws;                                  // 2048*4096
  u16* wqb = xb  + (size_t)S_LEN * DM;            // 4096*4096
  u16* wkb = wqb + (size_t)EQ * DM;               // 1024*4096
  u16* wvb = wkb + (size_t)EKV * DM;              // 1024*4096
  u16* wob = wvb + (size_t)EKV * DM;              // 4096*4096
  u16* qb  = wob + (size_t)DM * EQ;               // 2048*4096
  u16* kb  = qb  + (size_t)S_LEN * EQ;            // 2048*1024
  u16* vb  = kb  + (size_t)S_LEN * EKV;           // 2048*1024
  u16* vtb = vb  + (size_t)S_LEN * EKV;           // 1024*2048
  u16* aob = vtb + (size_t)S_LEN * EKV;           // 2048*4096

  cast_all<<<2048, 256, 0, stream>>>(x, wq, wk, wv, wo, xb, wqb, wkb, wvb, wob);
  // fused QKV projection: B = [wq;wk;wv] (6144 x 4096), BM=128/BN=192 -> 32x16 = 512 blocks (2/CU)
  gemm2p<3, true><<<dim3(32, 16), 256, 0, stream>>>(xb, wqb, qb, kb, vb, DM);
  rope_all<<<5120, 256, 0, stream>>>(qb, kb, cosb, sinb, sidx);
  transpose_v<<<dim3(EKV / 32, S_LEN / 32), dim3(32, 8), 0, stream>>>(vb, vtb);
  attn_fwd<<<dim3(16, NH), 256, 0, stream>>>(qb, kb, vtb, aob);
  // O projection: BM=128/BN=128 -> 32x16 = 512 blocks (2/CU)
  gemm2p<2, false><<<dim3(32, 16), 256, 0, stream>>>(aob, wob, out, nullptr, nullptr, EQ);
}